// Round 8
// baseline (374.692 us; speedup 1.0000x reference)
//
#include <hip/hip_runtime.h>

typedef __bf16 bf16x8 __attribute__((ext_vector_type(8)));
typedef float  f32x4  __attribute__((ext_vector_type(4)));
typedef float  f32x8  __attribute__((ext_vector_type(8)));
typedef unsigned short ushort;
typedef ushort us8 __attribute__((ext_vector_type(8)));

constexpr int N_NODES = 50000;
constexpr int N_EDGES = 800000;
constexpr int SLOTS = 64;                     // bucket capacity (mean deg 16, Poisson)
constexpr int NCH = 12;                       // 12 feature-chunks of 8
constexpr int NB = (N_NODES + 255) / 256;     // 196 node blocks
constexpr int GE = N_EDGES / 256;             // 3125 (exact)
constexpr int WBLK = (3 * 9216) / 256;        // 108 (exact)

__device__ inline float h16f(ushort u) {
    union { _Float16 h; ushort u; } cv; cv.u = u; return (float)cv.h;
}
__device__ inline ushort f16b(float f) {
    union { _Float16 h; ushort u; } cv; cv.h = (_Float16)f; return cv.u;
}
__device__ inline ushort bf16b(float f) {
    union { __bf16 b; ushort u; } cv; cv.b = (__bf16)f; return cv.u;
}

// ---------------- count (+rank) + W-prep ----------------
__global__ __launch_bounds__(256) void k_count(const int* __restrict__ dst,
                                               int* __restrict__ cnt,
                                               ushort* __restrict__ rank,
                                               const float* __restrict__ W0,
                                               const float* __restrict__ W1,
                                               const float* __restrict__ W2,
                                               ushort* __restrict__ Wt) {
    const int b = blockIdx.x;
    if (b < GE) {
        int e = b * 256 + threadIdx.x;
        rank[e] = (ushort)atomicAdd(&cnt[dst[e]], 1);
    } else {
        int i = (b - GE) * 256 + threadIdx.x;   // i < 3*9216 exactly
        int m = i / 9216, li = i - m * 9216;
        const float* W = (m == 0) ? W0 : (m == 1) ? W1 : W2;
        int k = li / 96, c = li - k * 96;
        Wt[m * 9216 + c * 96 + k] = bf16b(W[li]);
    }
}

// ---------------- fill: packed entry = src | f16(dinv[src])<<16, atomic-free ----------------
__global__ __launch_bounds__(256) void k_fill(const int* __restrict__ src,
                                              const int* __restrict__ dst,
                                              const int* __restrict__ cnt,
                                              const ushort* __restrict__ rank,
                                              unsigned int* __restrict__ csr) {
    int e = blockIdx.x * 256 + threadIdx.x;   // GE*256 == N_EDGES, exact
    int s = src[e], d = dst[e];
    float hs = rsqrtf((float)(cnt[s] + 1));
    unsigned int entry = (unsigned int)(ushort)s | ((unsigned int)f16b(hs) << 16);
    csr[(size_t)d * SLOTS + rank[e]] = entry;
}

// ---------------- MFMA GEMM -> bf16 chunk-transposed output ----------------
// IN 0: fp32 row-major  IN 1: bf16 chunk-transposed [c][n][8]
template<int IN>
__global__ __launch_bounds__(256) void k_gemm_mfma(const void* Xv, const ushort* __restrict__ Wt,
                                                   ushort* __restrict__ Y, int nrows) {
    __shared__ ushort sX[64 * 96];   // 12 KB
    __shared__ ushort sW[96 * 96];   // 18 KB, [c][k]
    const int tid = threadIdx.x;
    const int rowbase = blockIdx.x * 64;

    for (int i = tid; i < 96 * 96 / 8; i += 256)
        ((uint4*)sW)[i] = ((const uint4*)Wt)[i];

    if (IN == 0) {
        const float* X = (const float*)Xv;
        for (int i = tid; i < 64 * 24; i += 256) {
            int r = i / 24, c4 = i % 24;
            int gr = rowbase + r;
            float4 v = make_float4(0.f, 0.f, 0.f, 0.f);
            if (gr < nrows) v = ((const float4*)(X + (size_t)gr * 96))[c4];
            ushort* p = sX + r * 96 + c4 * 4;
            p[0] = bf16b(v.x); p[1] = bf16b(v.y); p[2] = bf16b(v.z); p[3] = bf16b(v.w);
        }
    } else {
        const ushort* X = (const ushort*)Xv;
        for (int i = tid; i < NCH * 64; i += 256) {
            int c = i >> 6, rr = i & 63;
            int gr = rowbase + rr;
            us8 v = (us8){0, 0, 0, 0, 0, 0, 0, 0};
            if (gr < nrows) v = *(const us8*)(X + ((size_t)c * N_NODES + gr) * 8);
            *(us8*)(sX + rr * 96 + c * 8) = v;
        }
    }
    __syncthreads();

    const int wv = tid >> 6, lane = tid & 63, quad = lane >> 4, l16 = lane & 15;
    f32x4 acc[6];
#pragma unroll
    for (int t = 0; t < 6; ++t) acc[t] = (f32x4){0.f, 0.f, 0.f, 0.f};

    const ushort* ax = sX + (wv * 16 + l16) * 96 + quad * 8;
#pragma unroll
    for (int s = 0; s < 3; ++s) {
        bf16x8 a = *(const bf16x8*)(ax + s * 32);
#pragma unroll
        for (int t = 0; t < 6; ++t) {
            bf16x8 b = *(const bf16x8*)(sW + (t * 16 + l16) * 96 + s * 32 + quad * 8);
            acc[t] = __builtin_amdgcn_mfma_f32_16x16x32_bf16(a, b, acc[t], 0, 0, 0);
        }
    }
    // C/D: col = t*16 + l16, row = r0 + g ; store chunk-transposed
    const int r0 = rowbase + wv * 16 + quad * 4;
#pragma unroll
    for (int t = 0; t < 6; ++t) {
        const int col = t * 16 + l16;
        const int cc = col >> 3, ff = col & 7;
#pragma unroll
        for (int g = 0; g < 4; ++g) {
            int r = r0 + g;
            if (r < nrows) Y[((size_t)cc * N_NODES + r) * 8 + ff] = bf16b(acc[t][g]);
        }
    }
}

// ---------------- bf16->f32 helper ----------------
__device__ inline f32x8 bf8_to_f32(us8 u) {
    f32x8 r;
#pragma unroll
    for (int i = 0; i < 8; ++i) r[i] = __uint_as_float(((unsigned int)u[i]) << 16);
    return r;
}

// ---------------- chunk-transposed aggregate ----------------
// block = 256 nodes x 1 chunk; chunk = blockIdx % 12 (XCD sees only 3 chunk-regions).
// OUT 0: bf16 transposed   OUT 1: fp32 transposed (pre-fc, no rounding)
template<int OUT>
__global__ __launch_bounds__(256) void k_aggT(const ushort* __restrict__ A,
                                              const int* __restrict__ cnt,
                                              const unsigned int* __restrict__ csr,
                                              const float* __restrict__ bias,
                                              ushort* __restrict__ O16,
                                              float* __restrict__ O32) {
    const int c = blockIdx.x % NCH;
    const int n = (blockIdx.x / NCH) * 256 + threadIdx.x;
    if (n >= N_NODES) return;

    const int deg = cnt[n];
    const float dn = rsqrtf((float)(deg + 1));
    const ushort* Ac = A + (size_t)c * N_NODES * 8;

    f32x8 acc = bf8_to_f32(*(const us8*)(Ac + (size_t)n * 8)) * (dn * dn);

    const unsigned int* row = csr + (size_t)n * SLOTS;
    int j = 0;
    for (; j + 8 <= deg; j += 8) {
        uint4 q0 = *(const uint4*)(row + j);
        uint4 q1 = *(const uint4*)(row + j + 4);
        unsigned int es[8] = {q0.x, q0.y, q0.z, q0.w, q1.x, q1.y, q1.z, q1.w};
        us8 u[8];
#pragma unroll
        for (int k = 0; k < 8; ++k)
            u[k] = *(const us8*)(Ac + (size_t)(es[k] & 0xFFFFu) * 8);
#pragma unroll
        for (int k = 0; k < 8; ++k) {
            const float w = h16f((ushort)(es[k] >> 16)) * dn;
            acc += bf8_to_f32(u[k]) * w;
        }
    }
    for (; j < deg; ++j) {
        const unsigned int e = row[j];
        const float w = h16f((ushort)(e >> 16)) * dn;
        const us8 u = *(const us8*)(Ac + (size_t)(e & 0xFFFFu) * 8);
        acc += bf8_to_f32(u) * w;
    }
#pragma unroll
    for (int f = 0; f < 8; ++f) acc[f] = fmaxf(acc[f] + bias[c * 8 + f], 0.0f);

    if (OUT == 0) {
        us8 o;
#pragma unroll
        for (int f = 0; f < 8; ++f) o[f] = bf16b(acc[f]);
        *(us8*)(O16 + ((size_t)c * N_NODES + n) * 8) = o;
    } else {
        *(f32x8*)(O32 + ((size_t)c * N_NODES + n) * 8) = acc;
    }
}

// ---------------- final FC over fp32 chunk-transposed H3 ----------------
__global__ __launch_bounds__(256) void k_fc(const float* __restrict__ H,
                                            const float* __restrict__ Wfc,
                                            const float* __restrict__ bfc,
                                            float4* __restrict__ out) {
    __shared__ float sW[384];
    __shared__ float sb[4];
    const int tid = threadIdx.x;
    for (int i = tid; i < 384; i += 256) sW[i] = Wfc[i];
    if (tid < 4) sb[tid] = bfc[tid];
    __syncthreads();

    const int n = blockIdx.x * 256 + tid;
    if (n >= N_NODES) return;
    float acc[4] = {sb[0], sb[1], sb[2], sb[3]};
#pragma unroll
    for (int c = 0; c < NCH; ++c) {
        f32x8 h = *(const f32x8*)(H + ((size_t)c * N_NODES + n) * 8);
#pragma unroll
        for (int f = 0; f < 8; ++f) {
            const float* wr = sW + (c * 8 + f) * 4;
            acc[0] += h[f] * wr[0];
            acc[1] += h[f] * wr[1];
            acc[2] += h[f] * wr[2];
            acc[3] += h[f] * wr[3];
        }
    }
    out[n] = make_float4(acc[0], acc[1], acc[2], acc[3]);
}

// ---------------- launch ----------------
extern "C" void kernel_launch(void* const* d_in, const int* in_sizes, int n_in,
                              void* d_out, int out_size, void* d_ws, size_t ws_size,
                              hipStream_t stream) {
    const float* x   = (const float*)d_in[0];
    const int*   ei  = (const int*)d_in[1];
    const int*   src = ei;
    const int*   dst = ei + N_EDGES;
    const float* W0  = (const float*)d_in[2];
    const float* b0  = (const float*)d_in[3];
    const float* W1  = (const float*)d_in[4];
    const float* b1  = (const float*)d_in[5];
    const float* W2  = (const float*)d_in[6];
    const float* b2  = (const float*)d_in[7];
    const float* Wfc = (const float*)d_in[8];
    const float* bfc = (const float*)d_in[9];
    float* out = (float*)d_out;

    // workspace layout (16 B-aligned blocks)
    char* w = (char*)d_ws;
    unsigned int* csr = (unsigned int*)w;  w += ((size_t)N_NODES * SLOTS * 4 + 15) & ~15ULL;
    int*    cnt  = (int*)w;                w += ((size_t)N_NODES * 4 + 15) & ~15ULL;
    ushort* rank = (ushort*)w;             w += ((size_t)N_EDGES * 2 + 15) & ~15ULL;
    ushort* Wt   = (ushort*)w;             w += ((size_t)3 * 9216 * 2 + 15) & ~15ULL;
    ushort* H    = (ushort*)w;             w += ((size_t)N_NODES * 96 * 2 + 15) & ~15ULL;
    ushort* G    = (ushort*)w;             w += ((size_t)N_NODES * 96 * 2 + 15) & ~15ULL;
    float*  H3   = (float*)w;              // N_NODES * 96 fp32, chunk-transposed

    const int gMf  = (N_NODES + 63) / 64;   // 782
    const int gAgg = NB * NCH;              // 2352

    hipMemsetAsync(cnt, 0, (size_t)N_NODES * 4, stream);
    hipLaunchKernelGGL(k_count, dim3(GE + WBLK), dim3(256), 0, stream,
                       dst, cnt, rank, W0, W1, W2, Wt);
    hipLaunchKernelGGL(k_fill,  dim3(GE), dim3(256), 0, stream,
                       src, dst, cnt, rank, csr);

    // Layer 1
    hipLaunchKernelGGL((k_gemm_mfma<0>), dim3(gMf), dim3(256), 0, stream,
                       (const void*)x, Wt, H, N_NODES);
    hipLaunchKernelGGL((k_aggT<0>), dim3(gAgg), dim3(256), 0, stream,
                       H, cnt, csr, b0, G, (float*)nullptr);
    // Layer 2
    hipLaunchKernelGGL((k_gemm_mfma<1>), dim3(gMf), dim3(256), 0, stream,
                       (const void*)G, Wt + 9216, H, N_NODES);
    hipLaunchKernelGGL((k_aggT<0>), dim3(gAgg), dim3(256), 0, stream,
                       H, cnt, csr, b1, G, (float*)nullptr);
    // Layer 3 (agg keeps fp32) + fc
    hipLaunchKernelGGL((k_gemm_mfma<1>), dim3(gMf), dim3(256), 0, stream,
                       (const void*)G, Wt + 2 * 9216, H, N_NODES);
    hipLaunchKernelGGL((k_aggT<1>), dim3(gAgg), dim3(256), 0, stream,
                       H, cnt, csr, b2, (ushort*)nullptr, H3);
    hipLaunchKernelGGL(k_fc, dim3(NB), dim3(256), 0, stream, H3, Wfc, bfc, (float4*)out);
}

// Round 9
// 243.638 us; speedup vs baseline: 1.5379x; 1.5379x over previous
//
#include <hip/hip_runtime.h>

typedef __bf16 bf16x8 __attribute__((ext_vector_type(8)));
typedef float  f32x4  __attribute__((ext_vector_type(4)));
typedef float  f32x8  __attribute__((ext_vector_type(8)));
typedef unsigned short ushort;
typedef ushort us8 __attribute__((ext_vector_type(8)));

constexpr int N_NODES = 50000;
constexpr int N_EDGES = 800000;
constexpr int SLOTS = 64;                     // bucket capacity (mean deg 16, Poisson tail < 64)
constexpr int GE = N_EDGES / 256;             // 3125 (exact)
constexpr int WBLK = (3 * 9216) / 256;        // 108 (exact)

__device__ inline float h16f(ushort u) {
    union { _Float16 h; ushort u; } cv; cv.u = u; return (float)cv.h;
}
__device__ inline ushort f16b(float f) {
    union { _Float16 h; ushort u; } cv; cv.h = (_Float16)f; return cv.u;
}
__device__ inline ushort bf16b(float f) {
    union { __bf16 b; ushort u; } cv; cv.b = (__bf16)f; return cv.u;
}

// ---------------- count (+rank) + W-prep ----------------
__global__ __launch_bounds__(256) void k_count(const int* __restrict__ dst,
                                               int* __restrict__ cnt,
                                               ushort* __restrict__ rank,
                                               const float* __restrict__ W0,
                                               const float* __restrict__ W1,
                                               const float* __restrict__ W2,
                                               ushort* __restrict__ Wt) {
    const int b = blockIdx.x;
    if (b < GE) {
        int e = b * 256 + threadIdx.x;
        rank[e] = (ushort)atomicAdd(&cnt[dst[e]], 1);
    } else {
        int i = (b - GE) * 256 + threadIdx.x;   // exact
        int m = i / 9216, li = i - m * 9216;
        const float* W = (m == 0) ? W0 : (m == 1) ? W1 : W2;
        int k = li / 96, c = li - k * 96;
        Wt[m * 9216 + c * 96 + k] = bf16b(W[li]);
    }
}

// ---------------- fill: packed entry = src | f16(dinv[src])<<16, atomic-free ----------------
__global__ __launch_bounds__(256) void k_fill(const int* __restrict__ src,
                                              const int* __restrict__ dst,
                                              const int* __restrict__ cnt,
                                              const ushort* __restrict__ rank,
                                              unsigned int* __restrict__ csr) {
    int e = blockIdx.x * 256 + threadIdx.x;   // GE*256 == N_EDGES, exact
    int s = src[e], d = dst[e];
    float hs = rsqrtf((float)(cnt[s] + 1));
    unsigned int entry = (unsigned int)(ushort)s | ((unsigned int)f16b(hs) << 16);
    csr[(size_t)d * SLOTS + rank[e]] = entry;
}

// ---------------- MFMA GEMM: Y[n,96] = X[n,96] @ W[96,96], bf16 row-major out ----------------
// 256 threads = 4 waves; 64-row tile; wave: 16 rows x 96 cols (6 tiles x 3 ksteps).
template<int IN>   // 0: fp32 in, 1: bf16 in
__global__ __launch_bounds__(256) void k_gemm_mfma(const void* Xv, const ushort* __restrict__ Wt,
                                                   ushort* __restrict__ Y, int nrows) {
    __shared__ ushort sX[64 * 96];   // 12 KB
    __shared__ ushort sW[96 * 96];   // 18 KB, [c][k]
    const int tid = threadIdx.x;
    const int rowbase = blockIdx.x * 64;

    for (int i = tid; i < 96 * 96 / 8; i += 256)
        ((uint4*)sW)[i] = ((const uint4*)Wt)[i];

    if (IN == 0) {
        const float* X = (const float*)Xv;
        for (int i = tid; i < 64 * 24; i += 256) {
            int r = i / 24, c4 = i % 24;
            int gr = rowbase + r;
            float4 v = make_float4(0.f, 0.f, 0.f, 0.f);
            if (gr < nrows) v = ((const float4*)(X + (size_t)gr * 96))[c4];
            ushort* p = sX + r * 96 + c4 * 4;
            p[0] = bf16b(v.x); p[1] = bf16b(v.y); p[2] = bf16b(v.z); p[3] = bf16b(v.w);
        }
    } else {
        const ushort* X = (const ushort*)Xv;
        for (int i = tid; i < 64 * 12; i += 256) {
            int r = i / 12, c8 = i % 12;
            int gr = rowbase + r;
            uint4 v = make_uint4(0, 0, 0, 0);
            if (gr < nrows) v = ((const uint4*)(X + (size_t)gr * 96))[c8];
            ((uint4*)(sX + r * 96))[c8] = v;
        }
    }
    __syncthreads();

    const int wv = tid >> 6, lane = tid & 63, quad = lane >> 4, l16 = lane & 15;
    f32x4 acc[6];
#pragma unroll
    for (int t = 0; t < 6; ++t) acc[t] = (f32x4){0.f, 0.f, 0.f, 0.f};

    const ushort* ax = sX + (wv * 16 + l16) * 96 + quad * 8;
#pragma unroll
    for (int s = 0; s < 3; ++s) {
        bf16x8 a = *(const bf16x8*)(ax + s * 32);
#pragma unroll
        for (int t = 0; t < 6; ++t) {
            bf16x8 b = *(const bf16x8*)(sW + (t * 16 + l16) * 96 + s * 32 + quad * 8);
            acc[t] = __builtin_amdgcn_mfma_f32_16x16x32_bf16(a, b, acc[t], 0, 0, 0);
        }
    }
    // C/D layout: col = lane&15, row = quad*4 + reg
    const int r0 = rowbase + wv * 16 + quad * 4;
#pragma unroll
    for (int t = 0; t < 6; ++t) {
#pragma unroll
        for (int g = 0; g < 4; ++g) {
            int r = r0 + g;
            if (r < nrows) Y[(size_t)r * 96 + t * 16 + l16] = bf16b(acc[t][g]);
        }
    }
}

// ---------------- bf16->f32 helper ----------------
__device__ inline f32x8 bf8_to_f32(us8 u) {
    f32x8 r;
#pragma unroll
    for (int i = 0; i < 8; ++i) r[i] = __uint_as_float(((unsigned int)u[i]) << 16);
    return r;
}

// ---------------- fused aggregate over row-major bf16 H (bucket CSR, packed) ----------------
// 192 threads = 16 nodes x 12 chunks of 8 feats. N_NODES % 16 == 0 -> exact grid.
// MODE 0: out = bf16 H'   MODE 1: fused final fc -> out4
template<int MODE>
__global__ __launch_bounds__(192) void k_agg(const ushort* __restrict__ A,
                                             const int* __restrict__ cnt,
                                             const unsigned int* __restrict__ csr,
                                             const float* __restrict__ bias,
                                             ushort* __restrict__ Hout,
                                             float* __restrict__ out4,
                                             const float* __restrict__ Wfc,
                                             const float* __restrict__ bfc) {
    __shared__ float sWfc[384];
    __shared__ float red[16][12][4];
    const int tid = threadIdx.x;
    if (MODE == 1) {
        for (int i = tid; i < 384; i += 192) sWfc[i] = Wfc[i];
        __syncthreads();
    }
    const int g = tid / 12, c = tid % 12;
    const int n = blockIdx.x * 16 + g;

    const int deg = cnt[n];
    const float dn = rsqrtf((float)(deg + 1));
    us8 a0 = *(const us8*)(A + (size_t)n * 96 + c * 8);
    f32x8 acc = bf8_to_f32(a0) * (dn * dn);

    const unsigned int* row = csr + (size_t)n * SLOTS;
    int j = 0;
    for (; j + 4 <= deg; j += 4) {
        const uint4 q = *(const uint4*)(row + j);       // broadcast across 12 chunk-threads
        const us8 u0 = *(const us8*)(A + (size_t)(q.x & 0xFFFFu) * 96 + c * 8);
        const us8 u1 = *(const us8*)(A + (size_t)(q.y & 0xFFFFu) * 96 + c * 8);
        const us8 u2 = *(const us8*)(A + (size_t)(q.z & 0xFFFFu) * 96 + c * 8);
        const us8 u3 = *(const us8*)(A + (size_t)(q.w & 0xFFFFu) * 96 + c * 8);
        acc += bf8_to_f32(u0) * (h16f((ushort)(q.x >> 16)) * dn);
        acc += bf8_to_f32(u1) * (h16f((ushort)(q.y >> 16)) * dn);
        acc += bf8_to_f32(u2) * (h16f((ushort)(q.z >> 16)) * dn);
        acc += bf8_to_f32(u3) * (h16f((ushort)(q.w >> 16)) * dn);
    }
    for (; j < deg; ++j) {
        const unsigned int e = row[j];
        const float w = h16f((ushort)(e >> 16)) * dn;
        const us8 u = *(const us8*)(A + (size_t)(e & 0xFFFFu) * 96 + c * 8);
        acc += bf8_to_f32(u) * w;
    }
#pragma unroll
    for (int f = 0; f < 8; ++f) acc[f] = fmaxf(acc[f] + bias[c * 8 + f], 0.0f);

    if (MODE == 0) {
        us8 o;
#pragma unroll
        for (int f = 0; f < 8; ++f) o[f] = bf16b(acc[f]);
        *(us8*)(Hout + (size_t)n * 96 + c * 8) = o;
    } else {
        float p0 = 0.f, p1 = 0.f, p2 = 0.f, p3 = 0.f;
#pragma unroll
        for (int f = 0; f < 8; ++f) {
            const float* wr = sWfc + (c * 8 + f) * 4;
            p0 += acc[f] * wr[0];
            p1 += acc[f] * wr[1];
            p2 += acc[f] * wr[2];
            p3 += acc[f] * wr[3];
        }
        red[g][c][0] = p0; red[g][c][1] = p1; red[g][c][2] = p2; red[g][c][3] = p3;
        __syncthreads();
        if (tid < 64) {
            const int gg = tid >> 2, jj = tid & 3;
            float s = bfc[jj];
#pragma unroll
            for (int cc = 0; cc < 12; ++cc) s += red[gg][cc][jj];
            out4[(size_t)(blockIdx.x * 16 + gg) * 4 + jj] = s;
        }
    }
}

// ---------------- launch ----------------
extern "C" void kernel_launch(void* const* d_in, const int* in_sizes, int n_in,
                              void* d_out, int out_size, void* d_ws, size_t ws_size,
                              hipStream_t stream) {
    const float* x   = (const float*)d_in[0];
    const int*   ei  = (const int*)d_in[1];
    const int*   src = ei;
    const int*   dst = ei + N_EDGES;
    const float* W0  = (const float*)d_in[2];
    const float* b0  = (const float*)d_in[3];
    const float* W1  = (const float*)d_in[4];
    const float* b1  = (const float*)d_in[5];
    const float* W2  = (const float*)d_in[6];
    const float* b2  = (const float*)d_in[7];
    const float* Wfc = (const float*)d_in[8];
    const float* bfc = (const float*)d_in[9];
    float* out = (float*)d_out;

    // workspace layout (16 B-aligned blocks)
    char* w = (char*)d_ws;
    unsigned int* csr = (unsigned int*)w;  w += ((size_t)N_NODES * SLOTS * 4 + 15) & ~15ULL;
    int*    cnt  = (int*)w;                w += ((size_t)N_NODES * 4 + 15) & ~15ULL;
    ushort* rank = (ushort*)w;             w += ((size_t)N_EDGES * 2 + 15) & ~15ULL;
    ushort* Wt   = (ushort*)w;             w += ((size_t)3 * 9216 * 2 + 15) & ~15ULL;
    ushort* H    = (ushort*)w;             w += ((size_t)N_NODES * 96 * 2 + 15) & ~15ULL;
    ushort* G    = (ushort*)w;             // N_NODES * 96 bf16

    const int gMf  = (N_NODES + 63) / 64;   // 782
    const int gAgg = N_NODES / 16;          // 3125, exact

    hipMemsetAsync(cnt, 0, (size_t)N_NODES * 4, stream);
    hipLaunchKernelGGL(k_count, dim3(GE + WBLK), dim3(256), 0, stream,
                       dst, cnt, rank, W0, W1, W2, Wt);
    hipLaunchKernelGGL(k_fill,  dim3(GE), dim3(256), 0, stream,
                       src, dst, cnt, rank, csr);

    // Layer 1
    hipLaunchKernelGGL((k_gemm_mfma<0>), dim3(gMf), dim3(256), 0, stream,
                       (const void*)x, Wt, H, N_NODES);
    hipLaunchKernelGGL((k_agg<0>), dim3(gAgg), dim3(192), 0, stream,
                       H, cnt, csr, b0, G, (float*)nullptr,
                       (const float*)nullptr, (const float*)nullptr);
    // Layer 2
    hipLaunchKernelGGL((k_gemm_mfma<1>), dim3(gMf), dim3(256), 0, stream,
                       (const void*)G, Wt + 9216, H, N_NODES);
    hipLaunchKernelGGL((k_agg<0>), dim3(gAgg), dim3(192), 0, stream,
                       H, cnt, csr, b1, G, (float*)nullptr,
                       (const float*)nullptr, (const float*)nullptr);
    // Layer 3 + fused fc
    hipLaunchKernelGGL((k_gemm_mfma<1>), dim3(gMf), dim3(256), 0, stream,
                       (const void*)G, Wt + 2 * 9216, H, N_NODES);
    hipLaunchKernelGGL((k_agg<1>), dim3(gAgg), dim3(192), 0, stream,
                       H, cnt, csr, b2, (ushort*)nullptr, out, Wfc, bfc);
}